// Round 10
// baseline (2610.149 us; speedup 1.0000x reference)
//
#include <hip/hip_runtime.h>
#include <hip/hip_bf16.h>
#include <stdint.h>

// 2-layer LSTM, B=1024 T=80 E=100 U=512, bf16 MFMA path.
// R1: layer2(t-1) || layer1(t) software pipeline (81 launches).
// R3/R8: pipeline-depth & register read-ahead: neutral -> not latency-bound.
// R4: 128x128 z-tile -> 1778us; time tracks staged bytes.
// R5-R7: persistence attempts regressed (fence/inv semantics); abandoned.
// R9: BK=64, half the barriers: neutral (1765us) -> not sync-bound.
// R10: 2-D XCD partition: REGRESSED 2348 -> blockIdx%8->XCD wrong (likely chunked);
//      decode reverted to R9's (which forms good rectangles under chunked mapping).
// R11: port rebalance. FETCH=15MB vs 104MB staged -> L1/L2 absorb staging; largest
//      per-kt port term is LDS: 128KB/kt/CU (A,B writes + A-reads x4 + B-reads x2).
//      Keep A staged (x4 reuse); load B fragments DIRECT global->VGPR (x2 reuse,
//      absorbed by per-CU L1: both wm-waves issue identical B addresses). LDS
//      traffic 128->80KB/kt; B rides the separate L1/vector path (16KB/kt unique).
//      B regs double-buffered one kt ahead (2x unroll, named sets). A ring depth-3
//      with counted vmcnt; tail counts {8,6,4} re-derived for the mixed stream.

#define B_ 1024
#define T_ 80

using bf16 = __hip_bfloat16;
typedef __attribute__((ext_vector_type(8))) short short8;
typedef __attribute__((ext_vector_type(4))) float f32x4;
typedef __attribute__((ext_vector_type(8))) unsigned short ushort8v;

__device__ __forceinline__ float sigf(float x) { return 1.f / (1.f + __expf(-x)); }
__device__ __forceinline__ float tanh_f(float x) { return 2.f / (1.f + __expf(-2.f * x)) - 1.f; }

typedef const __attribute__((address_space(1))) void* gp1_t;
typedef __attribute__((address_space(3))) void* lp3_t;
__device__ __forceinline__ void llds16(const void* g, void* l) {
  // per-lane global gather -> LDS wave-uniform base + lane*16
  __builtin_amdgcn_global_load_lds((gp1_t)g, (lp3_t)l, 16, 0, 0);
}

// XP[t][b][e] (e padded to 128 with zeros), bf16. Vectorized: thread = 8 elems.
__global__ void embed_kernel(const int* __restrict__ tokens, const float* __restrict__ emb,
                             bf16* __restrict__ XP) {
  int idx = blockIdx.x * 256 + threadIdx.x;  // over T_*B_*16
  int j = idx & 15;                          // e0 = j*8
  int bt = idx >> 4;
  int b = bt & (B_ - 1);
  int t = bt >> 10;
  if (t >= T_) return;
  int tok = tokens[b * T_ + t];
  int e0 = j * 8;
  float v[8];
  if (e0 + 8 <= 100) {
    *(float4*)(v) = *(const float4*)(emb + (size_t)tok * 100 + e0);
    *(float4*)(v + 4) = *(const float4*)(emb + (size_t)tok * 100 + e0 + 4);
  } else if (e0 < 100) {  // e0 == 96: 4 real + 4 zero
    *(float4*)(v) = *(const float4*)(emb + (size_t)tok * 100 + e0);
    v[4] = v[5] = v[6] = v[7] = 0.f;
  } else {
#pragma unroll
    for (int k = 0; k < 8; ++k) v[k] = 0.f;
  }
  ushort8v o;
#pragma unroll
  for (int k = 0; k < 8; ++k) {
    bf16 hb = __float2bfloat16(v[k]);
    o[k] = *(unsigned short*)&hb;
  }
  *(ushort8v*)(XP + (size_t)bt * 128 + e0) = o;
}

// W [Kreal][2048] fp32 -> WT [2048][Kp] bf16, coalesced both ways via 32x32 LDS tile
__global__ void transpose_kernel(const float* __restrict__ W, bf16* __restrict__ WT,
                                 int Kreal, int Kp) {
  __shared__ float tile[32][33];
  int tn = blockIdx.x * 32;
  int tk = blockIdx.y * 32;
  int lx = threadIdx.x & 31;
  int ly = threadIdx.x >> 5;  // 8
#pragma unroll
  for (int r = ly; r < 32; r += 8) {
    int k = tk + r;
    tile[r][lx] = (k < Kreal) ? W[(size_t)k * 2048 + tn + lx] : 0.f;
  }
  __syncthreads();
#pragma unroll
  for (int r = ly; r < 32; r += 8) {
    WT[(size_t)(tn + r) * Kp + tk + lx] = __float2bfloat16(tile[lx][r]);
  }
}

struct CellParams {
  const bf16* A0; const bf16* B0;
  const bf16* A1; const bf16* B1;
  int lda0, ldb0, nkt0, lda1, ldb1, nkt1;  // nkt in units of BK=64
  const float* bias; float* C; bf16* H;
};

// z = A0@B0^T-seg + A1@B1^T-seg + bias; gates i,f,g,o; C fp32 in-place; H bf16 out.
// Block tile 128 rows x 32 units (128 z-cols). Dual-cell: blocks 0..127 -> p0,
// 128..255 -> p1 (grid 128 on edge launches: p0 only). 512 threads = 8 waves
// 2(m)x4(n); wave = 4x2 16x16 frags.
// A: staged via global_load_lds, BK=64 (2 llds16/wave/stage), ring 4x16KB = 64KB.
// B: DIRECT global->VGPR per-lane gathers (short8), one kt ahead (bCur/bNxt).
//    Lane (q,m) of wave wn, frag (nj,s): row = wn*512 + u0 + nj*16 + m,
//    k-off = kt*64 + s*32 + q*8 -- identical addresses across wm pair -> L1 hits.
// K-loop top wait: pending = stageA(kt+1)[2] + stageA(kt+2)[2] + B(kt)[4] -> vmcnt(8)
// certifies stageA(kt); tail {6,4}. Compiler inserts the B-register waits.
// Epilogue: single pass via z[128][132] f32 (68KB, reuses A-ring after sync).
__global__ __launch_bounds__(512, 1) void cell_kernel(CellParams p0, CellParams p1) {
  __shared__ alignas(16) char smem[69632];
  const CellParams& p = (blockIdx.x >> 7) ? p1 : p0;
  const int lb = blockIdx.x & 127;
  const int g = (lb & 7) | ((lb >> 6) << 3);  // unit-group 0..15 (R9 decode)
  const int bm = (lb >> 3) & 7;               // 128-row tile 0..7
  const int u0 = g * 32;                      // unit offset
  const int tid = threadIdx.x;
  const int w = tid >> 6, l = tid & 63, q = l >> 4, m = l & 15;
  const int wm = w >> 2, wn = w & 3;

  // A staging rows: wave w stages rows bm*128 + w*16 + m
  const bf16* arow0 = p.A0 + (size_t)(bm * 128 + w * 16 + m) * p.lda0;
  const bf16* arow1 = p.A1 + (size_t)(bm * 128 + w * 16 + m) * p.lda1;

  // B direct row pointers for this thread's two nj frags
  const int bcol = wn * 512 + u0 + m;
  const bf16* b0r[2] = {p.B0 + (size_t)bcol * p.ldb0, p.B0 + (size_t)(bcol + 16) * p.ldb0};
  const bf16* b1r[2] = {p.B1 + (size_t)bcol * p.ldb1, p.B1 + (size_t)(bcol + 16) * p.ldb1};

  auto stage = [&](int kt, int buf) {
    const bf16* ga;
    if (kt < p.nkt0) ga = arow0 + kt * 64 + q * 8;
    else             ga = arow1 + (kt - p.nkt0) * 64 + q * 8;
    char* ab = smem + buf * 16384 + w * 2048;
    llds16(ga, ab);              // A s=0 (k 0..31 of this BK)
    llds16(ga + 32, ab + 1024);  // A s=1 (k 32..63)
  };

  auto loadB = [&](int kt, short8 (&bb)[4]) {
    if (kt < p.nkt0) {
      const int off = kt * 64 + q * 8;
#pragma unroll
      for (int nj = 0; nj < 2; ++nj) {
        bb[nj * 2 + 0] = *(const short8*)(b0r[nj] + off);
        bb[nj * 2 + 1] = *(const short8*)(b0r[nj] + off + 32);
      }
    } else {
      const int off = (kt - p.nkt0) * 64 + q * 8;
#pragma unroll
      for (int nj = 0; nj < 2; ++nj) {
        bb[nj * 2 + 0] = *(const short8*)(b1r[nj] + off);
        bb[nj * 2 + 1] = *(const short8*)(b1r[nj] + off + 32);
      }
    }
  };

  f32x4 acc[4][2];
#pragma unroll
  for (int mi = 0; mi < 4; ++mi)
#pragma unroll
    for (int nj = 0; nj < 2; ++nj) acc[mi][nj] = (f32x4){0.f, 0.f, 0.f, 0.f};

  const int fbase = q * 256 + m * 16;
  const int total = p.nkt0 + p.nkt1;  // 10 (layer1) or 16 (layer2), both EVEN

  auto kbody = [&](int kt, short8 (&bc)[4], short8 (&bn)[4]) {
    const int rem = total - 1 - kt;
    // pending at this point: stageA(kt+1)[2] + stageA(kt+2)[2] + B(kt)[4]
    if (rem >= 2)      asm volatile("s_waitcnt vmcnt(8)" ::: "memory");
    else if (rem == 1) asm volatile("s_waitcnt vmcnt(6)" ::: "memory");
    else               asm volatile("s_waitcnt vmcnt(4)" ::: "memory");
    __builtin_amdgcn_s_barrier();       // ALL waves' stageA(kt) landed
    __builtin_amdgcn_sched_barrier(0);  // keep ds_reads below the barrier
    if (kt + 3 < total) stage(kt + 3, (kt + 3) & 3);
    if (kt + 1 < total) loadB(kt + 1, bn);
    const int cb = (kt & 3) * 16384;
    short8 a0[4], a1[4];
#pragma unroll
    for (int mi = 0; mi < 4; ++mi)
      a0[mi] = *(const short8*)(smem + cb + (wm * 4 + mi) * 2048 + fbase);
#pragma unroll
    for (int mi = 0; mi < 4; ++mi)
      a1[mi] = *(const short8*)(smem + cb + (wm * 4 + mi) * 2048 + 1024 + fbase);
    // MFMA: s=0 uses bc[nj*2], s=1 uses bc[nj*2+1] (compiler waits B regs)
#pragma unroll
    for (int mi = 0; mi < 4; ++mi)
#pragma unroll
      for (int nj = 0; nj < 2; ++nj)
        acc[mi][nj] = __builtin_amdgcn_mfma_f32_16x16x32_bf16(a0[mi], bc[nj * 2 + 0], acc[mi][nj], 0, 0, 0);
#pragma unroll
    for (int mi = 0; mi < 4; ++mi)
#pragma unroll
      for (int nj = 0; nj < 2; ++nj)
        acc[mi][nj] = __builtin_amdgcn_mfma_f32_16x16x32_bf16(a1[mi], bc[nj * 2 + 1], acc[mi][nj], 0, 0, 0);
  };

  short8 bCur[4], bNxt[4];
  stage(0, 0);
  stage(1, 1);
  stage(2, 2);
  loadB(0, bCur);
  for (int kt = 0; kt < total; kt += 2) {
    kbody(kt, bCur, bNxt);
    kbody(kt + 1, bNxt, bCur);
  }

  __syncthreads();  // all frag reads done -> safe to overwrite ring with z
  float* zs = (float*)smem;  // [128][132] f32 = 67.6 KB
#pragma unroll
  for (int mi = 0; mi < 4; ++mi)
#pragma unroll
    for (int nj = 0; nj < 2; ++nj)
#pragma unroll
      for (int r = 0; r < 4; ++r)
        zs[(wm * 64 + mi * 16 + q * 4 + r) * 132 + wn * 32 + nj * 16 + m] = acc[mi][nj][r];
  __syncthreads();

  // one thread per (row, 8-unit chunk): 512 threads = 128 rows x 4 chunks
  const int erow = tid >> 2;
  const int ub8 = (tid & 3) * 8;
  const int gu0 = u0 + ub8;
  float bi[8], bfv[8], bg[8], bo[8];
  *(float4*)(bi) = *(const float4*)(p.bias + gu0);
  *(float4*)(bi + 4) = *(const float4*)(p.bias + gu0 + 4);
  *(float4*)(bfv) = *(const float4*)(p.bias + 512 + gu0);
  *(float4*)(bfv + 4) = *(const float4*)(p.bias + 512 + gu0 + 4);
  *(float4*)(bg) = *(const float4*)(p.bias + 1024 + gu0);
  *(float4*)(bg + 4) = *(const float4*)(p.bias + 1024 + gu0 + 4);
  *(float4*)(bo) = *(const float4*)(p.bias + 1536 + gu0);
  *(float4*)(bo + 4) = *(const float4*)(p.bias + 1536 + gu0 + 4);

  float zr[32];
  const float* zrow = zs + erow * 132;
  *(float4*)(zr) = *(const float4*)(zrow + ub8);            // i gate
  *(float4*)(zr + 4) = *(const float4*)(zrow + ub8 + 4);
  *(float4*)(zr + 8) = *(const float4*)(zrow + 32 + ub8);   // f gate
  *(float4*)(zr + 12) = *(const float4*)(zrow + 32 + ub8 + 4);
  *(float4*)(zr + 16) = *(const float4*)(zrow + 64 + ub8);  // g gate
  *(float4*)(zr + 20) = *(const float4*)(zrow + 64 + ub8 + 4);
  *(float4*)(zr + 24) = *(const float4*)(zrow + 96 + ub8);  // o gate
  *(float4*)(zr + 28) = *(const float4*)(zrow + 96 + ub8 + 4);

  const int grow = bm * 128 + erow;
  const size_t gi = (size_t)grow * 512 + gu0;
  float cold[8], cn[8];
  *(float4*)(cold) = *(const float4*)(p.C + gi);
  *(float4*)(cold + 4) = *(const float4*)(p.C + gi + 4);
  unsigned short hv[8];
#pragma unroll
  for (int jj = 0; jj < 8; ++jj) {
    float zi = zr[jj] + bi[jj];
    float zf = zr[8 + jj] + bfv[jj];
    float zg = zr[16 + jj] + bg[jj];
    float zo = zr[24 + jj] + bo[jj];
    float c = sigf(zf) * cold[jj] + sigf(zi) * tanh_f(zg);
    float h = sigf(zo) * tanh_f(c);
    cn[jj] = c;
    bf16 hb = __float2bfloat16(h);
    hv[jj] = *(unsigned short*)&hb;
  }
  *(float4*)(p.C + gi) = make_float4(cn[0], cn[1], cn[2], cn[3]);
  *(float4*)(p.C + gi + 4) = make_float4(cn[4], cn[5], cn[6], cn[7]);
  *(ushort8v*)(p.H + gi) = (ushort8v){hv[0], hv[1], hv[2], hv[3], hv[4], hv[5], hv[6], hv[7]};
}

// out[b] = sigmoid(h2[b,:] @ Wout + bout); one wave per row
__global__ void output_kernel(const bf16* __restrict__ H2, const float* __restrict__ Wout,
                              const float* __restrict__ bout, float* __restrict__ out) {
  int w = threadIdx.x >> 6, l = threadIdx.x & 63;
  int row = blockIdx.x * 4 + w;
  const bf16* h = H2 + (size_t)row * 512;
  float s = 0.f;
#pragma unroll
  for (int k = 0; k < 8; ++k) {
    int kk = l + k * 64;
    s += __bfloat162float(h[kk]) * Wout[kk];
  }
#pragma unroll
  for (int off = 32; off > 0; off >>= 1) s += __shfl_down(s, off);
  if (l == 0) out[row] = sigf(s + bout[0]);
}

extern "C" void kernel_launch(void* const* d_in, const int* in_sizes, int n_in,
                              void* d_out, int out_size, void* d_ws, size_t ws_size,
                              hipStream_t stream) {
  const int* tokens = (const int*)d_in[0];
  const float* emb = (const float*)d_in[1];
  const float* W1 = (const float*)d_in[2];
  const float* U1 = (const float*)d_in[3];
  const float* b1 = (const float*)d_in[4];
  const float* W2 = (const float*)d_in[5];
  const float* U2 = (const float*)d_in[6];
  const float* b2 = (const float*)d_in[7];
  const float* Wout = (const float*)d_in[8];
  const float* bout = (const float*)d_in[9];
  float* out = (float*)d_out;
  char* ws = (char*)d_ws;

  const size_t oXP = 0;          // 80*1024*128 bf16 = 20971520
  const size_t oW1T = 20971520;  // 2048*128 bf16
  const size_t oU1T = 21495808;  // 2048*512 bf16
  const size_t oW2T = 23592960;
  const size_t oU2T = 25690112;
  const size_t oH1 = 27787264;   // 2 x 1024*512 bf16
  const size_t oH2 = 29884416;
  const size_t oC1 = 31981568;   // 1024*512 f32
  const size_t oC2 = 34078720;
  if (ws_size < 36175872) return;

  bf16* XP = (bf16*)(ws + oXP);
  bf16* W1T = (bf16*)(ws + oW1T);
  bf16* U1T = (bf16*)(ws + oU1T);
  bf16* W2T = (bf16*)(ws + oW2T);
  bf16* U2T = (bf16*)(ws + oU2T);
  bf16* H1 = (bf16*)(ws + oH1);
  bf16* H2 = (bf16*)(ws + oH2);
  float* C1 = (float*)(ws + oC1);
  float* C2 = (float*)(ws + oC2);

  hipMemsetAsync(ws + oH1, 0, 1048576, stream);  // H1 buf0
  hipMemsetAsync(ws + oH2, 0, 1048576, stream);  // H2 buf0
  hipMemsetAsync(ws + oC1, 0, 4194304, stream);  // C1 + C2

  embed_kernel<<<5120, 256, 0, stream>>>(tokens, emb, XP);
  transpose_kernel<<<dim3(64, 4), 256, 0, stream>>>(W1, W1T, 100, 128);
  transpose_kernel<<<dim3(64, 16), 256, 0, stream>>>(U1, U1T, 512, 512);
  transpose_kernel<<<dim3(64, 16), 256, 0, stream>>>(W2, W2T, 512, 512);
  transpose_kernel<<<dim3(64, 16), 256, 0, stream>>>(U2, U2T, 512, 512);

  auto mkL1 = [&](int t) {
    CellParams p;
    p.A0 = XP + (size_t)t * 131072; p.B0 = W1T; p.lda0 = 128; p.ldb0 = 128; p.nkt0 = 2;
    p.A1 = H1 + (size_t)(t & 1) * 524288; p.B1 = U1T; p.lda1 = 512; p.ldb1 = 512; p.nkt1 = 8;
    p.bias = b1; p.C = C1; p.H = H1 + (size_t)((t + 1) & 1) * 524288;
    return p;
  };
  auto mkL2 = [&](int t) {
    CellParams p;
    p.A0 = H1 + (size_t)((t + 1) & 1) * 524288; p.B0 = W2T; p.lda0 = 512; p.ldb0 = 512; p.nkt0 = 8;
    p.A1 = H2 + (size_t)(t & 1) * 524288; p.B1 = U2T; p.lda1 = 512; p.ldb1 = 512; p.nkt1 = 8;
    p.bias = b2; p.C = C2; p.H = H2 + (size_t)((t + 1) & 1) * 524288;
    return p;
  };

  cell_kernel<<<128, 512, 0, stream>>>(mkL1(0), mkL1(0));
  for (int k = 1; k < T_; ++k)
    cell_kernel<<<256, 512, 0, stream>>>(mkL2(k - 1), mkL1(k));  // layer2(k-1) || layer1(k)
  cell_kernel<<<128, 512, 0, stream>>>(mkL2(T_ - 1), mkL2(T_ - 1));

  // final h2 in buffer (T_&1)==0
  output_kernel<<<256, 256, 0, stream>>>(H2, Wout, bout, out);
}

// Round 11
// 1760.387 us; speedup vs baseline: 1.4827x; 1.4827x over previous
//
#include <hip/hip_runtime.h>
#include <hip/hip_bf16.h>
#include <stdint.h>

// 2-layer LSTM, B=1024 T=80 E=100 U=512, bf16 MFMA path.
// R1: layer2(t-1) || layer1(t) software pipeline (81 launches).
// R3/R8: pipeline-depth & register read-ahead: neutral -> not latency-bound.
// R4: 128x128 z-tile -> 1778us; time tracks staged bytes.
// R5-R7: persistence attempts regressed (fence/inv semantics); abandoned.
// R9: BK=64, half the barriers: 1765us (best). Not sync-bound.
// R10: 2-D XCD stride-8 partition: REGRESSED 2348us -> blockIdx->XCD is chunked;
//      R9's natural decode already forms optimal {4bm x 8g x 1role} rectangles.
// R11: B direct global->VGPR: REGRESSED 2610us -> per-lane short8 gathers issue
//      ~4x more VMEM requests/byte than wave-wide global_load_lds; staging must
//      stay on the coalesced load_lds path.
// R12: revert to R9 exactly (best-known). Cost model from R4/R9/pre-R4 fits
//      t = ~10us fixed + ~10.7us/MB-per-CU staged; both terms ~10us and all
//      enumerated levers on either term are refuted or risk accuracy. ~310 TF
//      effective on K=1024 GEMM shapes = at the shape-class plateau.

#define B_ 1024
#define T_ 80

using bf16 = __hip_bfloat16;
typedef __attribute__((ext_vector_type(8))) short short8;
typedef __attribute__((ext_vector_type(4))) float f32x4;
typedef __attribute__((ext_vector_type(8))) unsigned short ushort8v;

__device__ __forceinline__ float sigf(float x) { return 1.f / (1.f + __expf(-x)); }
__device__ __forceinline__ float tanh_f(float x) { return 2.f / (1.f + __expf(-2.f * x)) - 1.f; }

typedef const __attribute__((address_space(1))) void* gp1_t;
typedef __attribute__((address_space(3))) void* lp3_t;
__device__ __forceinline__ void llds16(const void* g, void* l) {
  // per-lane global gather -> LDS wave-uniform base + lane*16
  __builtin_amdgcn_global_load_lds((gp1_t)g, (lp3_t)l, 16, 0, 0);
}

// XP[t][b][e] (e padded to 128 with zeros), bf16. Vectorized: thread = 8 elems.
__global__ void embed_kernel(const int* __restrict__ tokens, const float* __restrict__ emb,
                             bf16* __restrict__ XP) {
  int idx = blockIdx.x * 256 + threadIdx.x;  // over T_*B_*16
  int j = idx & 15;                          // e0 = j*8
  int bt = idx >> 4;
  int b = bt & (B_ - 1);
  int t = bt >> 10;
  if (t >= T_) return;
  int tok = tokens[b * T_ + t];
  int e0 = j * 8;
  float v[8];
  if (e0 + 8 <= 100) {
    *(float4*)(v) = *(const float4*)(emb + (size_t)tok * 100 + e0);
    *(float4*)(v + 4) = *(const float4*)(emb + (size_t)tok * 100 + e0 + 4);
  } else if (e0 < 100) {  // e0 == 96: 4 real + 4 zero
    *(float4*)(v) = *(const float4*)(emb + (size_t)tok * 100 + e0);
    v[4] = v[5] = v[6] = v[7] = 0.f;
  } else {
#pragma unroll
    for (int k = 0; k < 8; ++k) v[k] = 0.f;
  }
  ushort8v o;
#pragma unroll
  for (int k = 0; k < 8; ++k) {
    bf16 hb = __float2bfloat16(v[k]);
    o[k] = *(unsigned short*)&hb;
  }
  *(ushort8v*)(XP + (size_t)bt * 128 + e0) = o;
}

// W [Kreal][2048] fp32 -> WT [2048][Kp] bf16, coalesced both ways via 32x32 LDS tile
__global__ void transpose_kernel(const float* __restrict__ W, bf16* __restrict__ WT,
                                 int Kreal, int Kp) {
  __shared__ float tile[32][33];
  int tn = blockIdx.x * 32;
  int tk = blockIdx.y * 32;
  int lx = threadIdx.x & 31;
  int ly = threadIdx.x >> 5;  // 8
#pragma unroll
  for (int r = ly; r < 32; r += 8) {
    int k = tk + r;
    tile[r][lx] = (k < Kreal) ? W[(size_t)k * 2048 + tn + lx] : 0.f;
  }
  __syncthreads();
#pragma unroll
  for (int r = ly; r < 32; r += 8) {
    WT[(size_t)(tn + r) * Kp + tk + lx] = __float2bfloat16(tile[lx][r]);
  }
}

struct CellParams {
  const bf16* A0; const bf16* B0;
  const bf16* A1; const bf16* B1;
  int lda0, ldb0, nkt0, lda1, ldb1, nkt1;  // nkt in units of BK=64
  const float* bias; float* C; bf16* H;
};

// z = A0@B0^T-seg + A1@B1^T-seg + bias; gates i,f,g,o; C fp32 in-place; H bf16 out.
// Block tile 128 rows x 32 units (128 z-cols). Dual-cell: blocks 0..127 -> p0,
// 128..255 -> p1. 512 threads = 8 waves 2(m)x4(n); wave = 4x2 16x16 frags.
// BK=64: per stage, wave w stages its 16 A rows and 16 B n-rows as TWO k-subtiles
// (s=0,1), 4 llds16/wave. LDS buffer layout: A [w][s][q][m][16B] at w*2048+s*1024,
// B same at +16384; 32KB/buffer, 4-buffer ring = 128KB. Frag reads are lane-linear
// (conflict-free). K-loop: wait vmcnt(8) (2 stages in flight), barrier, stage(kt+3),
// read 12 frags, 16 MFMA. Tail peels vmcnt(4)/vmcnt(0).
// Epilogue: single pass via z[128][132] f32 (68KB, reuses ring after syncthreads).
__global__ __launch_bounds__(512, 1) void cell_kernel(CellParams p0, CellParams p1) {
  __shared__ alignas(16) char smem[131072];
  const CellParams& p = (blockIdx.x >> 7) ? p1 : p0;
  const int lb = blockIdx.x & 127;
  const int g = (lb & 7) | ((lb >> 6) << 3);  // unit-group 0..15
  const int bm = (lb >> 3) & 7;               // 128-row tile 0..7
  const int u0 = g * 32;                      // unit offset
  const int tid = threadIdx.x;
  const int w = tid >> 6, l = tid & 63, q = l >> 4, m = l & 15;
  const int wm = w >> 2, wn = w & 3;

  // staging rows: wave w stages A rows bm*128+w*16+m; B n-rows (w>>1)*512+u0+(w&1)*16+m
  const bf16* arow0 = p.A0 + (size_t)(bm * 128 + w * 16 + m) * p.lda0;
  const bf16* brow0 = p.B0 + (size_t)((w >> 1) * 512 + u0 + (w & 1) * 16 + m) * p.ldb0;
  const bf16* arow1 = p.A1 + (size_t)(bm * 128 + w * 16 + m) * p.lda1;
  const bf16* brow1 = p.B1 + (size_t)((w >> 1) * 512 + u0 + (w & 1) * 16 + m) * p.ldb1;

  auto stage = [&](int kt, int buf) {
    const bf16 *ga, *gb;
    if (kt < p.nkt0) { int k0 = kt * 64 + q * 8; ga = arow0 + k0; gb = brow0 + k0; }
    else { int k0 = (kt - p.nkt0) * 64 + q * 8; ga = arow1 + k0; gb = brow1 + k0; }
    char* ab = smem + buf * 32768 + w * 2048;
    llds16(ga, ab);                    // A s=0 (k 0..31 of this BK)
    llds16(ga + 32, ab + 1024);        // A s=1 (k 32..63)
    llds16(gb, ab + 16384);            // B s=0
    llds16(gb + 32, ab + 16384 + 1024);// B s=1
  };

  f32x4 acc[4][2];
#pragma unroll
  for (int mi = 0; mi < 4; ++mi)
#pragma unroll
    for (int nj = 0; nj < 2; ++nj) acc[mi][nj] = (f32x4){0.f, 0.f, 0.f, 0.f};

  const int fbase = q * 256 + m * 16;
  const int total = p.nkt0 + p.nkt1;  // 10 (layer1) or 16 (layer2)

  stage(0, 0);
  stage(1, 1);
  stage(2, 2);
  for (int kt = 0; kt < total; ++kt) {
    const int rem = total - 1 - kt;
    if (rem >= 2)      asm volatile("s_waitcnt vmcnt(8)" ::: "memory");  // stage kt landed
    else if (rem == 1) asm volatile("s_waitcnt vmcnt(4)" ::: "memory");
    else               asm volatile("s_waitcnt vmcnt(0)" ::: "memory");
    __builtin_amdgcn_s_barrier();       // ALL waves' stage(kt) landed
    __builtin_amdgcn_sched_barrier(0);  // keep ds_reads below the barrier
    if (kt + 3 < total) stage(kt + 3, (kt + 3) & 3);
    const int cb = (kt & 3) * 32768;
    short8 a0[4], b0[2], a1[4], b1[2];
#pragma unroll
    for (int mi = 0; mi < 4; ++mi)
      a0[mi] = *(const short8*)(smem + cb + (wm * 4 + mi) * 2048 + fbase);
#pragma unroll
    for (int nj = 0; nj < 2; ++nj)
      b0[nj] = *(const short8*)(smem + cb + 16384 + (wn * 2 + nj) * 2048 + fbase);
#pragma unroll
    for (int mi = 0; mi < 4; ++mi)
      a1[mi] = *(const short8*)(smem + cb + (wm * 4 + mi) * 2048 + 1024 + fbase);
#pragma unroll
    for (int nj = 0; nj < 2; ++nj)
      b1[nj] = *(const short8*)(smem + cb + 16384 + (wn * 2 + nj) * 2048 + 1024 + fbase);
#pragma unroll
    for (int mi = 0; mi < 4; ++mi)
#pragma unroll
      for (int nj = 0; nj < 2; ++nj)
        acc[mi][nj] = __builtin_amdgcn_mfma_f32_16x16x32_bf16(a0[mi], b0[nj], acc[mi][nj], 0, 0, 0);
#pragma unroll
    for (int mi = 0; mi < 4; ++mi)
#pragma unroll
      for (int nj = 0; nj < 2; ++nj)
        acc[mi][nj] = __builtin_amdgcn_mfma_f32_16x16x32_bf16(a1[mi], b1[nj], acc[mi][nj], 0, 0, 0);
  }

  __syncthreads();  // all frag reads done -> safe to overwrite ring with z
  float* zs = (float*)smem;  // [128][132] f32 = 67.6 KB
#pragma unroll
  for (int mi = 0; mi < 4; ++mi)
#pragma unroll
    for (int nj = 0; nj < 2; ++nj)
#pragma unroll
      for (int r = 0; r < 4; ++r)
        zs[(wm * 64 + mi * 16 + q * 4 + r) * 132 + wn * 32 + nj * 16 + m] = acc[mi][nj][r];
  __syncthreads();

  // one thread per (row, 8-unit chunk): 512 threads = 128 rows x 4 chunks
  const int erow = tid >> 2;
  const int ub8 = (tid & 3) * 8;
  const int gu0 = u0 + ub8;
  float bi[8], bfv[8], bg[8], bo[8];
  *(float4*)(bi) = *(const float4*)(p.bias + gu0);
  *(float4*)(bi + 4) = *(const float4*)(p.bias + gu0 + 4);
  *(float4*)(bfv) = *(const float4*)(p.bias + 512 + gu0);
  *(float4*)(bfv + 4) = *(const float4*)(p.bias + 512 + gu0 + 4);
  *(float4*)(bg) = *(const float4*)(p.bias + 1024 + gu0);
  *(float4*)(bg + 4) = *(const float4*)(p.bias + 1024 + gu0 + 4);
  *(float4*)(bo) = *(const float4*)(p.bias + 1536 + gu0);
  *(float4*)(bo + 4) = *(const float4*)(p.bias + 1536 + gu0 + 4);

  float zr[32];
  const float* zrow = zs + erow * 132;
  *(float4*)(zr) = *(const float4*)(zrow + ub8);            // i gate
  *(float4*)(zr + 4) = *(const float4*)(zrow + ub8 + 4);
  *(float4*)(zr + 8) = *(const float4*)(zrow + 32 + ub8);   // f gate
  *(float4*)(zr + 12) = *(const float4*)(zrow + 32 + ub8 + 4);
  *(float4*)(zr + 16) = *(const float4*)(zrow + 64 + ub8);  // g gate
  *(float4*)(zr + 20) = *(const float4*)(zrow + 64 + ub8 + 4);
  *(float4*)(zr + 24) = *(const float4*)(zrow + 96 + ub8);  // o gate
  *(float4*)(zr + 28) = *(const float4*)(zrow + 96 + ub8 + 4);

  const int grow = bm * 128 + erow;
  const size_t gi = (size_t)grow * 512 + gu0;
  float cold[8], cn[8];
  *(float4*)(cold) = *(const float4*)(p.C + gi);
  *(float4*)(cold + 4) = *(const float4*)(p.C + gi + 4);
  unsigned short hv[8];
#pragma unroll
  for (int jj = 0; jj < 8; ++jj) {
    float zi = zr[jj] + bi[jj];
    float zf = zr[8 + jj] + bfv[jj];
    float zg = zr[16 + jj] + bg[jj];
    float zo = zr[24 + jj] + bo[jj];
    float c = sigf(zf) * cold[jj] + sigf(zi) * tanh_f(zg);
    float h = sigf(zo) * tanh_f(c);
    cn[jj] = c;
    bf16 hb = __float2bfloat16(h);
    hv[jj] = *(unsigned short*)&hb;
  }
  *(float4*)(p.C + gi) = make_float4(cn[0], cn[1], cn[2], cn[3]);
  *(float4*)(p.C + gi + 4) = make_float4(cn[4], cn[5], cn[6], cn[7]);
  *(ushort8v*)(p.H + gi) = (ushort8v){hv[0], hv[1], hv[2], hv[3], hv[4], hv[5], hv[6], hv[7]};
}

// out[b] = sigmoid(h2[b,:] @ Wout + bout); one wave per row
__global__ void output_kernel(const bf16* __restrict__ H2, const float* __restrict__ Wout,
                              const float* __restrict__ bout, float* __restrict__ out) {
  int w = threadIdx.x >> 6, l = threadIdx.x & 63;
  int row = blockIdx.x * 4 + w;
  const bf16* h = H2 + (size_t)row * 512;
  float s = 0.f;
#pragma unroll
  for (int k = 0; k < 8; ++k) {
    int kk = l + k * 64;
    s += __bfloat162float(h[kk]) * Wout[kk];
  }
#pragma unroll
  for (int off = 32; off > 0; off >>= 1) s += __shfl_down(s, off);
  if (l == 0) out[row] = sigf(s + bout[0]);
}

extern "C" void kernel_launch(void* const* d_in, const int* in_sizes, int n_in,
                              void* d_out, int out_size, void* d_ws, size_t ws_size,
                              hipStream_t stream) {
  const int* tokens = (const int*)d_in[0];
  const float* emb = (const float*)d_in[1];
  const float* W1 = (const float*)d_in[2];
  const float* U1 = (const float*)d_in[3];
  const float* b1 = (const float*)d_in[4];
  const float* W2 = (const float*)d_in[5];
  const float* U2 = (const float*)d_in[6];
  const float* b2 = (const float*)d_in[7];
  const float* Wout = (const float*)d_in[8];
  const float* bout = (const float*)d_in[9];
  float* out = (float*)d_out;
  char* ws = (char*)d_ws;

  const size_t oXP = 0;          // 80*1024*128 bf16 = 20971520
  const size_t oW1T = 20971520;  // 2048*128 bf16
  const size_t oU1T = 21495808;  // 2048*512 bf16
  const size_t oW2T = 23592960;
  const size_t oU2T = 25690112;
  const size_t oH1 = 27787264;   // 2 x 1024*512 bf16
  const size_t oH2 = 29884416;
  const size_t oC1 = 31981568;   // 1024*512 f32
  const size_t oC2 = 34078720;
  if (ws_size < 36175872) return;

  bf16* XP = (bf16*)(ws + oXP);
  bf16* W1T = (bf16*)(ws + oW1T);
  bf16* U1T = (bf16*)(ws + oU1T);
  bf16* W2T = (bf16*)(ws + oW2T);
  bf16* U2T = (bf16*)(ws + oU2T);
  bf16* H1 = (bf16*)(ws + oH1);
  bf16* H2 = (bf16*)(ws + oH2);
  float* C1 = (float*)(ws + oC1);
  float* C2 = (float*)(ws + oC2);

  hipMemsetAsync(ws + oH1, 0, 1048576, stream);  // H1 buf0
  hipMemsetAsync(ws + oH2, 0, 1048576, stream);  // H2 buf0
  hipMemsetAsync(ws + oC1, 0, 4194304, stream);  // C1 + C2

  embed_kernel<<<5120, 256, 0, stream>>>(tokens, emb, XP);
  transpose_kernel<<<dim3(64, 4), 256, 0, stream>>>(W1, W1T, 100, 128);
  transpose_kernel<<<dim3(64, 16), 256, 0, stream>>>(U1, U1T, 512, 512);
  transpose_kernel<<<dim3(64, 16), 256, 0, stream>>>(W2, W2T, 512, 512);
  transpose_kernel<<<dim3(64, 16), 256, 0, stream>>>(U2, U2T, 512, 512);

  auto mkL1 = [&](int t) {
    CellParams p;
    p.A0 = XP + (size_t)t * 131072; p.B0 = W1T; p.lda0 = 128; p.ldb0 = 128; p.nkt0 = 2;
    p.A1 = H1 + (size_t)(t & 1) * 524288; p.B1 = U1T; p.lda1 = 512; p.ldb1 = 512; p.nkt1 = 8;
    p.bias = b1; p.C = C1; p.H = H1 + (size_t)((t + 1) & 1) * 524288;
    return p;
  };
  auto mkL2 = [&](int t) {
    CellParams p;
    p.A0 = H1 + (size_t)((t + 1) & 1) * 524288; p.B0 = W2T; p.lda0 = 512; p.ldb0 = 512; p.nkt0 = 8;
    p.A1 = H2 + (size_t)(t & 1) * 524288; p.B1 = U2T; p.lda1 = 512; p.ldb1 = 512; p.nkt1 = 8;
    p.bias = b2; p.C = C2; p.H = H2 + (size_t)((t + 1) & 1) * 524288;
    return p;
  };

  cell_kernel<<<128, 512, 0, stream>>>(mkL1(0), mkL1(0));
  for (int k = 1; k < T_; ++k)
    cell_kernel<<<256, 512, 0, stream>>>(mkL2(k - 1), mkL1(k));  // layer2(k-1) || layer1(k)
  cell_kernel<<<128, 512, 0, stream>>>(mkL2(T_ - 1), mkL2(T_ - 1));

  // final h2 in buffer (T_&1)==0
  output_kernel<<<256, 256, 0, stream>>>(H2, Wout, bout, out);
}